// Round 8
// baseline (235.538 us; speedup 1.0000x reference)
//
#include <hip/hip_runtime.h>
#include <math.h>

// MaxMarginLoss: B=4,S=512,D=512,V=32000, gamma=0.5, eps=1e-12
// score[r,v] = (out_norm[r] - tgt_emb[r]) . voc_norm[v]  -> argmax_v (first-idx ties)
// loss = mean over non-pad rows of max(gamma + cos(out,voc[jmax]) - cos(out,voc[tgt]), 0)
//
// R8 (gemm identical to R7 = best measured: BK=64, XOR swizzle, XCD strips):
//  - 3 dispatches: prep_all (voc + rows fused; block 0 zeroes scratch),
//    gemm_argmax (per-row best via global atomicMax on packed u64),
//    row_final_reduce (fp32 rescore at jmax + ticketed masked mean).

#define Bb 4
#define Ss 512
#define Dd 512
#define Vv 32000
#define ROWS (Bb * Ss)          // 2048
#define NTILE_M (ROWS / 128)    // 16
#define NTILE_N (Vv / 128)      // 250
#define VOC_BLOCKS (Vv / 4)     // 8000

typedef __attribute__((ext_vector_type(8))) short bf16x8;
typedef __attribute__((ext_vector_type(4))) float f32x4;

__device__ __forceinline__ float waveReduceSum(float x) {
#pragma unroll
  for (int m = 32; m >= 1; m >>= 1) x += __shfl_xor(x, m, 64);
  return x;
}

__device__ __forceinline__ unsigned short f2bf(float f) {
  unsigned u = __float_as_uint(f);
  unsigned r = (u + 0x7FFFu + ((u >> 16) & 1u)) >> 16;  // RNE; inputs finite
  return (unsigned short)r;
}

// monotonic key: for finite floats, key(a) < key(b) <=> a < b; key > 0 always
__device__ __forceinline__ unsigned long long packSC(float s, int c) {
  unsigned b = __float_as_uint(s);
  unsigned key = b ^ ((b & 0x80000000u) ? 0xFFFFFFFFu : 0x80000000u);
  return ((unsigned long long)key << 32) | (unsigned)(~c);  // ~c: ties -> smaller col wins at max
}

__device__ __forceinline__ void async_ld16(const void* g, void* l) {
  __builtin_amdgcn_global_load_lds((const __attribute__((address_space(1))) void*)g,
                                   (__attribute__((address_space(3))) void*)l, 16, 0, 0);
}

// K1: fused prep. blocks [0,8000): vocab -> ebf + inv_norm (block 0 also zeroes
// best[2048] + accum). blocks [8000,8512): 4 preds rows -> o_rows, u_bf, cos_tgt.
__global__ __launch_bounds__(256) void prep_all(
    const float* __restrict__ preds, const float* __restrict__ emb,
    const int* __restrict__ target,
    float* __restrict__ o_rows, short* __restrict__ u_bf,
    float* __restrict__ cos_tgt, short* __restrict__ ebf,
    float* __restrict__ inv_norm, unsigned long long* __restrict__ zero_region) {
  int tid = threadIdx.x;
  int wave = tid >> 6, lane = tid & 63;
  if (blockIdx.x < VOC_BLOCKS) {
    if (blockIdx.x == 0) {
      for (int i = tid; i < ROWS + 2; i += 256) zero_region[i] = 0ull;  // best + accum
    }
    int v = blockIdx.x * 4 + wave;
    const float* e = emb + (size_t)v * Dd;
    float4 x0 = *(const float4*)(e + lane * 8);
    float4 x1 = *(const float4*)(e + lane * 8 + 4);
    float ss = x0.x * x0.x + x0.y * x0.y + x0.z * x0.z + x0.w * x0.w +
               x1.x * x1.x + x1.y * x1.y + x1.z * x1.z + x1.w * x1.w;
    ss = waveReduceSum(ss);
    float inv = 1.0f / fmaxf(sqrtf(ss), 1e-12f);
    bf16x8 o;
    o[0] = (short)f2bf(x0.x * inv); o[1] = (short)f2bf(x0.y * inv);
    o[2] = (short)f2bf(x0.z * inv); o[3] = (short)f2bf(x0.w * inv);
    o[4] = (short)f2bf(x1.x * inv); o[5] = (short)f2bf(x1.y * inv);
    o[6] = (short)f2bf(x1.z * inv); o[7] = (short)f2bf(x1.w * inv);
    *(bf16x8*)(ebf + (size_t)v * Dd + lane * 8) = o;
    if (lane == 0) inv_norm[v] = inv;
  } else {
    int row0 = (blockIdx.x - VOC_BLOCKS) * 4;
    int b = row0 >> 9, s0 = row0 & (Ss - 1);
    const float* p = preds + (size_t)b * Dd * Ss;
    float4 x0 = *(const float4*)(p + (size_t)tid * Ss + s0);
    float4 x1 = *(const float4*)(p + (size_t)(tid + 256) * Ss + s0);
    float a0[4] = {x0.x, x0.y, x0.z, x0.w};
    float a1[4] = {x1.x, x1.y, x1.z, x1.w};
    __shared__ float rA[4][4], rB[4][4], rC[4][4];
    float sq[4];
#pragma unroll
    for (int j = 0; j < 4; ++j) sq[j] = waveReduceSum(a0[j] * a0[j] + a1[j] * a1[j]);
    if (lane == 0)
#pragma unroll
      for (int j = 0; j < 4; ++j) rA[wave][j] = sq[j];
    __syncthreads();
    float o0[4], o1[4];
#pragma unroll
    for (int j = 0; j < 4; ++j) {
      float inv = 1.0f / fmaxf(sqrtf(rA[0][j] + rA[1][j] + rA[2][j] + rA[3][j]), 1e-12f);
      o0[j] = a0[j] * inv;
      o1[j] = a1[j] * inv;
      o_rows[(size_t)(row0 + j) * Dd + tid] = o0[j];
      o_rows[(size_t)(row0 + j) * Dd + tid + 256] = o1[j];
    }
    float ss2[4], dt[4];
#pragma unroll
    for (int j = 0; j < 4; ++j) {
      int t = target[row0 + j];
      const float* et = emb + (size_t)t * Dd;
      float e0 = et[tid], e1 = et[tid + 256];
      u_bf[(size_t)(row0 + j) * Dd + tid] = (short)f2bf(o0[j] - e0);
      u_bf[(size_t)(row0 + j) * Dd + tid + 256] = (short)f2bf(o1[j] - e1);
      ss2[j] = waveReduceSum(e0 * e0 + e1 * e1);
      dt[j] = waveReduceSum(o0[j] * e0 + o1[j] * e1);
    }
    if (lane == 0)
#pragma unroll
      for (int j = 0; j < 4; ++j) { rB[wave][j] = ss2[j]; rC[wave][j] = dt[j]; }
    __syncthreads();
    if (tid < 4) {
      int j = tid;
      float n2 = rB[0][j] + rB[1][j] + rB[2][j] + rB[3][j];
      float dd = rC[0][j] + rC[1][j] + rC[2][j] + rC[3][j];
      cos_tgt[row0 + j] = dd * (1.0f / fmaxf(sqrtf(n2), 1e-12f));
    }
  }
}

// K2: 128x128-tile bf16 MFMA GEMM (B^T), BK=64, XOR bank swizzle, XCD strips,
// + argmax epilogue publishing per-row best via atomicMax(u64).
__global__ __launch_bounds__(256) void gemm_argmax(
    const short* __restrict__ u_bf, const short* __restrict__ ebf,
    unsigned long long* __restrict__ best) {
  __shared__ short sA[128 * 64];  // 16 KB
  __shared__ short sB[128 * 64];  // 16 KB
  int bid = blockIdx.x;
  int g = (bid & 7) * 500 + (bid >> 3);
  int tm = g & 15, tn = g >> 4;
  int tid = threadIdx.x;
  int w = tid >> 6, lane = tid & 63;
  int wm = w >> 1, wn = w & 1;

  // staging: glds dest = wave-base + lane*16 -> row = lane>>3, chunk = lane&7.
  // lane sources GLOBAL chunk (lane&7)^((lane>>3)&7) so that physical chunk
  // (lane&7) of row r holds logical chunk (lane&7)^(r&7).
  int srow = w * 8 + (lane >> 3);
  int schunk = (lane & 7) ^ ((lane >> 3) & 7);
  const short* gA = u_bf + (size_t)(tm * 128 + srow) * Dd + schunk * 8;
  const short* gB = ebf + (size_t)(tn * 128 + srow) * Dd + schunk * 8;

  // fragment read: row fr, k-quad q = lane>>4; logical chunk kc*4+q ->
  // physical (kc*4+q)^(fr&7).
  int fr = lane & 15;
  int q = lane >> 4;
  int ck0 = ((q) ^ (fr & 7)) * 8;
  int ck1 = ((4 + q) ^ (fr & 7)) * 8;

  f32x4 acc[4][4];
  f32x4 z = {0.f, 0.f, 0.f, 0.f};
#pragma unroll
  for (int mi = 0; mi < 4; ++mi)
#pragma unroll
    for (int ni = 0; ni < 4; ++ni) acc[mi][ni] = z;

  for (int kk = 0; kk < Dd / 64; ++kk) {
    __syncthreads();  // previous compute done before overwrite
    {
      const short* ga = gA + kk * 64;
      const short* gb = gB + kk * 64;
#pragma unroll
      for (int i = 0; i < 4; ++i) {
        async_ld16(ga + (size_t)(i * 32) * Dd, &sA[(w * 8 + i * 32) * 64]);
        async_ld16(gb + (size_t)(i * 32) * Dd, &sB[(w * 8 + i * 32) * 64]);
      }
    }
    __syncthreads();  // staging visible (vmcnt drained by barrier)
    bf16x8 af0[4], af1[4], bg0[4], bg1[4];
#pragma unroll
    for (int mi = 0; mi < 4; ++mi) {
      int r = (wm * 64 + mi * 16 + fr) * 64;
      af0[mi] = *(const bf16x8*)(sA + r + ck0);
      af1[mi] = *(const bf16x8*)(sA + r + ck1);
    }
#pragma unroll
    for (int ni = 0; ni < 4; ++ni) {
      int r = (wn * 64 + ni * 16 + fr) * 64;
      bg0[ni] = *(const bf16x8*)(sB + r + ck0);
      bg1[ni] = *(const bf16x8*)(sB + r + ck1);
    }
#pragma unroll
    for (int mi = 0; mi < 4; ++mi)
#pragma unroll
      for (int ni = 0; ni < 4; ++ni)
        acc[mi][ni] = __builtin_amdgcn_mfma_f32_16x16x32_bf16(af0[mi], bg0[ni], acc[mi][ni], 0, 0, 0);
#pragma unroll
    for (int mi = 0; mi < 4; ++mi)
#pragma unroll
      for (int ni = 0; ni < 4; ++ni)
        acc[mi][ni] = __builtin_amdgcn_mfma_f32_16x16x32_bf16(af1[mi], bg1[ni], acc[mi][ni], 0, 0, 0);
  }

  // ---- argmax epilogue ----
  // C layout: col = lane&15, row = (lane>>4)*4 + reg
  float bs[4][4];
  int bc[4][4];
  int col0 = tn * 128 + wn * 64 + (lane & 15);
#pragma unroll
  for (int mi = 0; mi < 4; ++mi) {
#pragma unroll
    for (int j = 0; j < 4; ++j) { bs[mi][j] = acc[mi][0][j]; bc[mi][j] = col0; }
#pragma unroll
    for (int ni = 1; ni < 4; ++ni) {
      int c = col0 + ni * 16;
#pragma unroll
      for (int j = 0; j < 4; ++j) {
        float v = acc[mi][ni][j];
        if (v > bs[mi][j]) { bs[mi][j] = v; bc[mi][j] = c; }  // strict >: earliest col kept
      }
    }
  }
#pragma unroll
  for (int m = 1; m < 16; m <<= 1) {
#pragma unroll
    for (int mi = 0; mi < 4; ++mi)
#pragma unroll
      for (int j = 0; j < 4; ++j) {
        float os = __shfl_xor(bs[mi][j], m, 64);
        int oc = __shfl_xor(bc[mi][j], m, 64);
        if (os > bs[mi][j] || (os == bs[mi][j] && oc < bc[mi][j])) {
          bs[mi][j] = os;
          bc[mi][j] = oc;
        }
      }
  }
  // merge the two col-half waves (wn=0/1) via LDS, one atomicMax per row
  __syncthreads();  // done reading sA/sB; reuse as merge scratch
  float* sEs = (float*)sA;          // [2][128]
  int* sEc = (int*)sA + 256;        // [2][128]
  if ((lane & 15) == 0) {
    int qq = lane >> 4;
#pragma unroll
    for (int mi = 0; mi < 4; ++mi)
#pragma unroll
      for (int j = 0; j < 4; ++j) {
        int rloc = wm * 64 + mi * 16 + qq * 4 + j;
        sEs[wn * 128 + rloc] = bs[mi][j];
        sEc[wn * 128 + rloc] = bc[mi][j];
      }
  }
  __syncthreads();
  if (tid < 128) {
    float s0 = sEs[tid], s1 = sEs[128 + tid];
    int c0 = sEc[tid], c1 = sEc[128 + tid];
    if (s1 > s0 || (s1 == s0 && c1 < c0)) { s0 = s1; c0 = c1; }
    atomicMax(&best[tm * 128 + tid], packSC(s0, c0));
  }
}

// K3: per row — read global best, recompute cos at jmax in fp32, hinge,
// device-wide masked mean via atomics + last-block ticket.
__global__ __launch_bounds__(256) void row_final_reduce(
    const float* __restrict__ o_rows, const float* __restrict__ emb,
    const float* __restrict__ inv_norm, const float* __restrict__ cos_tgt,
    const int* __restrict__ target, const int* __restrict__ pad_id,
    const unsigned long long* __restrict__ best, float* __restrict__ accum,
    float* __restrict__ out) {
  int wave = threadIdx.x >> 6, lane = threadIdx.x & 63;
  int row = blockIdx.x * 4 + wave;
  int bi = (int)(~(unsigned)(best[row] & 0xFFFFFFFFull));
  const float* o = o_rows + (size_t)row * Dd;
  const float* e = emb + (size_t)bi * Dd;
  float d = 0.f;
#pragma unroll
  for (int i = 0; i < Dd / 64; ++i) d += o[lane + 64 * i] * e[lane + 64 * i];
  d = waveReduceSum(d);
  __shared__ float sdf[4], scn[4];
  if (lane == 0) {
    float cmax = d * inv_norm[bi];
    int t = target[row];
    float df = fmaxf(0.5f + cmax - cos_tgt[row], 0.0f);
    bool ok = (t != pad_id[0]);
    sdf[wave] = ok ? df : 0.0f;
    scn[wave] = ok ? 1.0f : 0.0f;
  }
  __syncthreads();
  if (threadIdx.x == 0) {
    atomicAdd(&accum[0], sdf[0] + sdf[1] + sdf[2] + sdf[3]);
    atomicAdd(&accum[1], scn[0] + scn[1] + scn[2] + scn[3]);
    __threadfence();
    unsigned t = (unsigned)atomicAdd(&accum[2], 1.0f);
    if (t == (unsigned)(ROWS / 4 - 1)) {
      __threadfence();
      volatile float* va = accum;
      out[0] = va[0] / va[1];
    }
  }
}

extern "C" void kernel_launch(void* const* d_in, const int* in_sizes, int n_in,
                              void* d_out, int out_size, void* d_ws, size_t ws_size,
                              hipStream_t stream) {
  const float* preds = (const float*)d_in[0];
  const float* emb = (const float*)d_in[1];
  const int* target = (const int*)d_in[2];
  const int* pad_id = (const int*)d_in[3];
  char* ws = (char*)d_ws;
  // ws layout (bytes), total ~39.2 MB
  float* o_rows = (float*)ws;                               // 2048*512*4 = 4,194,304
  short* u_bf = (short*)(ws + 4194304);                     // 2048*512*2 = 2,097,152
  short* ebf = (short*)(ws + 6291456);                      // 32000*512*2 = 32,768,000
  float* inv_norm = (float*)(ws + 39059456);                // 32000*4 = 128,000
  float* cos_tgt = (float*)(ws + 39187456);                 // 2048*4 = 8,192
  unsigned long long* best = (unsigned long long*)(ws + 39195648);  // 2048*8 = 16,384
  float* accum = (float*)(ws + 39212032);                   // 4 floats (zeroed w/ best)

  prep_all<<<VOC_BLOCKS + ROWS / 4, 256, 0, stream>>>(preds, emb, target, o_rows,
                                                      u_bf, cos_tgt, ebf, inv_norm,
                                                      best);
  gemm_argmax<<<NTILE_M * NTILE_N, 256, 0, stream>>>(u_bf, ebf, best);
  row_final_reduce<<<ROWS / 4, 256, 0, stream>>>(o_rows, emb, inv_norm, cos_tgt,
                                                 target, pad_id, best, accum,
                                                 (float*)d_out);
}

// Round 9
// 206.853 us; speedup vs baseline: 1.1387x; 1.1387x over previous
//
#include <hip/hip_runtime.h>
#include <math.h>

// MaxMarginLoss: B=4,S=512,D=512,V=32000, gamma=0.5, eps=1e-12
// score[r,v] = (out_norm[r] - tgt_emb[r]) . voc_norm[v]  -> argmax_v (first-idx ties)
// loss = mean over non-pad rows of max(gamma + cos(out,voc[jmax]) - cos(out,voc[tgt]), 0)
//
// R9 = R7 (best measured, 220 us) + gemm register diet:
//  - one shared frag set reused across the two BK=64 halves (32 VGPR, was 64)
//  - __launch_bounds__(256,4): 4 waves/EU -> ~4 blocks/CU resident (was 2.4),
//    more waves to cover the staging-barrier drain.
// R8's fused-prep + atomic tail both regressed (measured) -> reverted to R7 tail.

#define Bb 4
#define Ss 512
#define Dd 512
#define Vv 32000
#define ROWS (Bb * Ss)          // 2048
#define NTILE_M (ROWS / 128)    // 16
#define NTILE_N (Vv / 128)      // 250

typedef __attribute__((ext_vector_type(8))) short bf16x8;
typedef __attribute__((ext_vector_type(4))) float f32x4;

__device__ __forceinline__ float waveReduceSum(float x) {
#pragma unroll
  for (int m = 32; m >= 1; m >>= 1) x += __shfl_xor(x, m, 64);
  return x;
}

__device__ __forceinline__ unsigned short f2bf(float f) {
  unsigned u = __float_as_uint(f);
  unsigned r = (u + 0x7FFFu + ((u >> 16) & 1u)) >> 16;  // RNE; inputs finite
  return (unsigned short)r;
}

// monotonic key: for finite floats, key(a) < key(b) <=> a < b
__device__ __forceinline__ unsigned long long packSC(float s, int c) {
  unsigned b = __float_as_uint(s);
  unsigned key = b ^ ((b & 0x80000000u) ? 0xFFFFFFFFu : 0x80000000u);
  return ((unsigned long long)key << 32) | (unsigned)(~c);  // ~c: ties -> smaller col wins at max
}

__device__ __forceinline__ void async_ld16(const void* g, void* l) {
  __builtin_amdgcn_global_load_lds((const __attribute__((address_space(1))) void*)g,
                                   (__attribute__((address_space(3))) void*)l, 16, 0, 0);
}

// A: per-row prep, 4 rows (same b) per block. float4 loads along S.
__global__ __launch_bounds__(256) void prep_rows(
    const float* __restrict__ preds, const float* __restrict__ emb,
    const int* __restrict__ target,
    float* __restrict__ o_rows, short* __restrict__ u_bf,
    float* __restrict__ cos_tgt) {
  int row0 = blockIdx.x * 4;       // 512 blocks
  int b = row0 >> 9, s0 = row0 & (Ss - 1);
  int tid = threadIdx.x;
  int wave = tid >> 6, lane = tid & 63;
  const float* p = preds + (size_t)b * Dd * Ss;
  float4 x0 = *(const float4*)(p + (size_t)tid * Ss + s0);         // d=tid
  float4 x1 = *(const float4*)(p + (size_t)(tid + 256) * Ss + s0); // d=tid+256
  float a0[4] = {x0.x, x0.y, x0.z, x0.w};
  float a1[4] = {x1.x, x1.y, x1.z, x1.w};
  __shared__ float rA[4][4], rB[4][4], rC[4][4];
  float sq[4];
#pragma unroll
  for (int j = 0; j < 4; ++j) sq[j] = waveReduceSum(a0[j] * a0[j] + a1[j] * a1[j]);
  if (lane == 0)
#pragma unroll
    for (int j = 0; j < 4; ++j) rA[wave][j] = sq[j];
  __syncthreads();
  float o0[4], o1[4];
#pragma unroll
  for (int j = 0; j < 4; ++j) {
    float inv = 1.0f / fmaxf(sqrtf(rA[0][j] + rA[1][j] + rA[2][j] + rA[3][j]), 1e-12f);
    o0[j] = a0[j] * inv;
    o1[j] = a1[j] * inv;
    o_rows[(size_t)(row0 + j) * Dd + tid] = o0[j];
    o_rows[(size_t)(row0 + j) * Dd + tid + 256] = o1[j];
  }
  float ss2[4], dt[4];
#pragma unroll
  for (int j = 0; j < 4; ++j) {
    int t = target[row0 + j];
    const float* et = emb + (size_t)t * Dd;
    float e0 = et[tid], e1 = et[tid + 256];
    u_bf[(size_t)(row0 + j) * Dd + tid] = (short)f2bf(o0[j] - e0);
    u_bf[(size_t)(row0 + j) * Dd + tid + 256] = (short)f2bf(o1[j] - e1);
    ss2[j] = waveReduceSum(e0 * e0 + e1 * e1);
    dt[j] = waveReduceSum(o0[j] * e0 + o1[j] * e1);
  }
  if (lane == 0)
#pragma unroll
    for (int j = 0; j < 4; ++j) { rB[wave][j] = ss2[j]; rC[wave][j] = dt[j]; }
  __syncthreads();
  if (tid < 4) {
    int j = tid;
    float n2 = rB[0][j] + rB[1][j] + rB[2][j] + rB[3][j];
    float dd = rC[0][j] + rC[1][j] + rC[2][j] + rC[3][j];
    cos_tgt[row0 + j] = dd * (1.0f / fmaxf(sqrtf(n2), 1e-12f));
  }
}

// B: voc_norm rows in bf16 + inv_norm fp32. One wave per v.
__global__ __launch_bounds__(256) void voc_prep(const float* __restrict__ emb,
                                                short* __restrict__ ebf,
                                                float* __restrict__ inv_norm) {
  int v = blockIdx.x * 4 + (threadIdx.x >> 6);
  int lane = threadIdx.x & 63;
  const float* e = emb + (size_t)v * Dd;
  float4 x0 = *(const float4*)(e + lane * 8);
  float4 x1 = *(const float4*)(e + lane * 8 + 4);
  float ss = x0.x * x0.x + x0.y * x0.y + x0.z * x0.z + x0.w * x0.w +
             x1.x * x1.x + x1.y * x1.y + x1.z * x1.z + x1.w * x1.w;
  ss = waveReduceSum(ss);
  float inv = 1.0f / fmaxf(sqrtf(ss), 1e-12f);
  bf16x8 o;
  o[0] = (short)f2bf(x0.x * inv); o[1] = (short)f2bf(x0.y * inv);
  o[2] = (short)f2bf(x0.z * inv); o[3] = (short)f2bf(x0.w * inv);
  o[4] = (short)f2bf(x1.x * inv); o[5] = (short)f2bf(x1.y * inv);
  o[6] = (short)f2bf(x1.z * inv); o[7] = (short)f2bf(x1.w * inv);
  *(bf16x8*)(ebf + (size_t)v * Dd + lane * 8) = o;
  if (lane == 0) inv_norm[v] = inv;
}

// C: 128x128-tile bf16 MFMA GEMM (B^T), BK=64, XOR bank swizzle, XCD strips,
// + argmax epilogue. Two fragment-load halves share ONE register set.
__global__ __launch_bounds__(256, 4) void gemm_argmax(
    const short* __restrict__ u_bf, const short* __restrict__ ebf,
    unsigned long long* __restrict__ part) {
  __shared__ short sA[128 * 64];  // 16 KB
  __shared__ short sB[128 * 64];  // 16 KB
  int bid = blockIdx.x;
  int g = (bid & 7) * 500 + (bid >> 3);
  int tm = g & 15, tn = g >> 4;
  int tid = threadIdx.x;
  int w = tid >> 6, lane = tid & 63;
  int wm = w >> 1, wn = w & 1;

  // staging: glds dest = wave-base + lane*16 -> row = lane>>3, chunk = lane&7.
  // lane sources GLOBAL chunk (lane&7)^((lane>>3)&7): physical chunk (lane&7)
  // of row r holds logical chunk (lane&7)^(r&7).
  int srow = w * 8 + (lane >> 3);
  int schunk = (lane & 7) ^ ((lane >> 3) & 7);
  const short* gA = u_bf + (size_t)(tm * 128 + srow) * Dd + schunk * 8;
  const short* gB = ebf + (size_t)(tn * 128 + srow) * Dd + schunk * 8;

  // fragment read: row fr, k-quad q = lane>>4; logical chunk kc*4+q ->
  // physical (kc*4+q)^(fr&7).
  int fr = lane & 15;
  int q = lane >> 4;
  int ck0 = ((q) ^ (fr & 7)) * 8;
  int ck1 = ((4 + q) ^ (fr & 7)) * 8;

  f32x4 acc[4][4];
  f32x4 z = {0.f, 0.f, 0.f, 0.f};
#pragma unroll
  for (int mi = 0; mi < 4; ++mi)
#pragma unroll
    for (int ni = 0; ni < 4; ++ni) acc[mi][ni] = z;

  for (int kk = 0; kk < Dd / 64; ++kk) {
    __syncthreads();  // previous compute done before overwrite
    {
      const short* ga = gA + kk * 64;
      const short* gb = gB + kk * 64;
#pragma unroll
      for (int i = 0; i < 4; ++i) {
        async_ld16(ga + (size_t)(i * 32) * Dd, &sA[(w * 8 + i * 32) * 64]);
        async_ld16(gb + (size_t)(i * 32) * Dd, &sB[(w * 8 + i * 32) * 64]);
      }
    }
    __syncthreads();  // staging visible (vmcnt drained by barrier)
    bf16x8 af[4], bg[4];
    // half 0 (kc=0)
#pragma unroll
    for (int mi = 0; mi < 4; ++mi)
      af[mi] = *(const bf16x8*)(sA + (wm * 64 + mi * 16 + fr) * 64 + ck0);
#pragma unroll
    for (int ni = 0; ni < 4; ++ni)
      bg[ni] = *(const bf16x8*)(sB + (wn * 64 + ni * 16 + fr) * 64 + ck0);
#pragma unroll
    for (int mi = 0; mi < 4; ++mi)
#pragma unroll
      for (int ni = 0; ni < 4; ++ni)
        acc[mi][ni] = __builtin_amdgcn_mfma_f32_16x16x32_bf16(af[mi], bg[ni], acc[mi][ni], 0, 0, 0);
    // half 1 (kc=1) — reuse the same registers
#pragma unroll
    for (int mi = 0; mi < 4; ++mi)
      af[mi] = *(const bf16x8*)(sA + (wm * 64 + mi * 16 + fr) * 64 + ck1);
#pragma unroll
    for (int ni = 0; ni < 4; ++ni)
      bg[ni] = *(const bf16x8*)(sB + (wn * 64 + ni * 16 + fr) * 64 + ck1);
#pragma unroll
    for (int mi = 0; mi < 4; ++mi)
#pragma unroll
      for (int ni = 0; ni < 4; ++ni)
        acc[mi][ni] = __builtin_amdgcn_mfma_f32_16x16x32_bf16(af[mi], bg[ni], acc[mi][ni], 0, 0, 0);
  }

  // ---- argmax epilogue ----
  // C layout: col = lane&15, row = (lane>>4)*4 + reg
  float bs[4][4];
  int bc[4][4];
  int col0 = tn * 128 + wn * 64 + (lane & 15);
#pragma unroll
  for (int mi = 0; mi < 4; ++mi) {
#pragma unroll
    for (int j = 0; j < 4; ++j) { bs[mi][j] = acc[mi][0][j]; bc[mi][j] = col0; }
#pragma unroll
    for (int ni = 1; ni < 4; ++ni) {
      int c = col0 + ni * 16;
#pragma unroll
      for (int j = 0; j < 4; ++j) {
        float v = acc[mi][ni][j];
        if (v > bs[mi][j]) { bs[mi][j] = v; bc[mi][j] = c; }  // strict >: earliest col kept
      }
    }
  }
  // butterfly across the 16 cols (masks 1,2,4,8 stay within the 16-lane group)
#pragma unroll
  for (int m = 1; m < 16; m <<= 1) {
#pragma unroll
    for (int mi = 0; mi < 4; ++mi)
#pragma unroll
      for (int j = 0; j < 4; ++j) {
        float os = __shfl_xor(bs[mi][j], m, 64);
        int oc = __shfl_xor(bc[mi][j], m, 64);
        if (os > bs[mi][j] || (os == bs[mi][j] && oc < bc[mi][j])) {
          bs[mi][j] = os;
          bc[mi][j] = oc;
        }
      }
  }
  // merge the two col-half waves (wn=0/1) via LDS, one packed write per row
  __syncthreads();  // done reading sA/sB; reuse as merge scratch
  float* sEs = (float*)sA;          // [2][128]
  int* sEc = (int*)sA + 256;        // [2][128]
  if ((lane & 15) == 0) {
    int qq = lane >> 4;
#pragma unroll
    for (int mi = 0; mi < 4; ++mi)
#pragma unroll
      for (int j = 0; j < 4; ++j) {
        int rloc = wm * 64 + mi * 16 + qq * 4 + j;
        sEs[wn * 128 + rloc] = bs[mi][j];
        sEc[wn * 128 + rloc] = bc[mi][j];
      }
  }
  __syncthreads();
  if (tid < 128) {
    float s0 = sEs[tid], s1 = sEs[128 + tid];
    int c0 = sEc[tid], c1 = sEc[128 + tid];
    if (s1 > s0 || (s1 == s0 && c1 < c0)) { s0 = s1; c0 = c1; }
    part[(size_t)tn * ROWS + tm * 128 + tid] = packSC(s0, c0);
  }
}

// D: per row — u64-max merge 250 partials, recompute cos at jmax in fp32, hinge.
__global__ __launch_bounds__(256) void row_final(
    const float* __restrict__ o_rows, const float* __restrict__ emb,
    const float* __restrict__ inv_norm, const float* __restrict__ cos_tgt,
    const int* __restrict__ target, const int* __restrict__ pad_id,
    const unsigned long long* __restrict__ part, float* __restrict__ diffs) {
  int wave = threadIdx.x >> 6, lane = threadIdx.x & 63;
  int row = blockIdx.x * 4 + wave;
  unsigned long long best = 0ull;  // any real packed value exceeds 0
  for (int t = lane; t < NTILE_N; t += 64) {
    unsigned long long p = part[(size_t)t * ROWS + row];
    if (p > best) best = p;
  }
#pragma unroll
  for (int m = 1; m < 64; m <<= 1) {
    unsigned long long o = __shfl_xor(best, m, 64);
    if (o > best) best = o;
  }
  int bi = (int)(~(unsigned)(best & 0xFFFFFFFFull));
  const float* o = o_rows + (size_t)row * Dd;
  const float* e = emb + (size_t)bi * Dd;
  float d = 0.f;
#pragma unroll
  for (int i = 0; i < Dd / 64; ++i) d += o[lane + 64 * i] * e[lane + 64 * i];
  d = waveReduceSum(d);
  if (lane == 0) {
    float cmax = d * inv_norm[bi];
    int t = target[row];
    float df = fmaxf(0.5f + cmax - cos_tgt[row], 0.0f);
    diffs[row] = (t != pad_id[0]) ? df : 0.0f;
  }
}

// F: masked mean.
__global__ __launch_bounds__(256) void reduce_final(
    const float* __restrict__ diffs, const int* __restrict__ target,
    const int* __restrict__ pad_id, float* __restrict__ out) {
  int tid = threadIdx.x;
  int pid = pad_id[0];
  float s = 0.f, c = 0.f;
  for (int i = tid; i < ROWS; i += 256) {
    s += diffs[i];
    c += (target[i] != pid) ? 1.0f : 0.0f;
  }
  s = waveReduceSum(s);
  c = waveReduceSum(c);
  __shared__ float rs[4], rc[4];
  int wave = tid >> 6, lane = tid & 63;
  if (lane == 0) { rs[wave] = s; rc[wave] = c; }
  __syncthreads();
  if (tid == 0) out[0] = (rs[0] + rs[1] + rs[2] + rs[3]) / (rc[0] + rc[1] + rc[2] + rc[3]);
}

extern "C" void kernel_launch(void* const* d_in, const int* in_sizes, int n_in,
                              void* d_out, int out_size, void* d_ws, size_t ws_size,
                              hipStream_t stream) {
  const float* preds = (const float*)d_in[0];
  const float* emb = (const float*)d_in[1];
  const int* target = (const int*)d_in[2];
  const int* pad_id = (const int*)d_in[3];
  char* ws = (char*)d_ws;
  // ws layout (bytes), total ~43.3 MB
  float* o_rows = (float*)ws;                               // 2048*512*4 = 4,194,304
  short* u_bf = (short*)(ws + 4194304);                     // 2048*512*2 = 2,097,152
  short* ebf = (short*)(ws + 6291456);                      // 32000*512*2 = 32,768,000
  float* inv_norm = (float*)(ws + 39059456);                // 32000*4 = 128,000
  float* cos_tgt = (float*)(ws + 39187456);                 // 2048*4
  unsigned long long* part = (unsigned long long*)(ws + 39195648);  // 250*2048*8 = 4,096,000
  float* diffs = (float*)(ws + 43291648);                   // 2048*4

  prep_rows<<<ROWS / 4, 256, 0, stream>>>(preds, emb, target, o_rows, u_bf, cos_tgt);
  voc_prep<<<Vv / 4, 256, 0, stream>>>(emb, ebf, inv_norm);
  gemm_argmax<<<NTILE_M * NTILE_N, 256, 0, stream>>>(u_bf, ebf, part);
  row_final<<<ROWS / 4, 256, 0, stream>>>(o_rows, emb, inv_norm, cos_tgt, target,
                                          pad_id, part, diffs);
  reduce_final<<<1, 256, 0, stream>>>(diffs, target, pad_id, (float*)d_out);
}

// Round 10
// 206.763 us; speedup vs baseline: 1.1392x; 1.0004x over previous
//
#include <hip/hip_runtime.h>
#include <math.h>

// MaxMarginLoss: B=4,S=512,D=512,V=32000, gamma=0.5, eps=1e-12
// score[r,v] = (out_norm[r] - tgt_emb[r]) . voc_norm[v]  -> argmax_v (first-idx ties)
// loss = mean over non-pad rows of max(gamma + cos(out,voc[jmax]) - cos(out,voc[tgt]), 0)
//
// R10 = R9 (gemm frozen: BK=64, XOR swizzle, XCD strips, frag-reg reuse,
// launch_bounds(256,4) -> 94 us) + ONE change: prep fused into a single
// light-register kernel (voc branch + R3-style 1-row prep branch, ~30 VGPR
// each -> no register coupling, unlike R8's heavy fusion). Tail unchanged.

#define Bb 4
#define Ss 512
#define Dd 512
#define Vv 32000
#define ROWS (Bb * Ss)          // 2048
#define NTILE_M (ROWS / 128)    // 16
#define NTILE_N (Vv / 128)      // 250
#define VOC_BLOCKS (Vv / 4)     // 8000

typedef __attribute__((ext_vector_type(8))) short bf16x8;
typedef __attribute__((ext_vector_type(4))) float f32x4;

__device__ __forceinline__ float waveReduceSum(float x) {
#pragma unroll
  for (int m = 32; m >= 1; m >>= 1) x += __shfl_xor(x, m, 64);
  return x;
}

__device__ __forceinline__ unsigned short f2bf(float f) {
  unsigned u = __float_as_uint(f);
  unsigned r = (u + 0x7FFFu + ((u >> 16) & 1u)) >> 16;  // RNE; inputs finite
  return (unsigned short)r;
}

// monotonic key: for finite floats, key(a) < key(b) <=> a < b
__device__ __forceinline__ unsigned long long packSC(float s, int c) {
  unsigned b = __float_as_uint(s);
  unsigned key = b ^ ((b & 0x80000000u) ? 0xFFFFFFFFu : 0x80000000u);
  return ((unsigned long long)key << 32) | (unsigned)(~c);  // ~c: ties -> smaller col wins at max
}

__device__ __forceinline__ void async_ld16(const void* g, void* l) {
  __builtin_amdgcn_global_load_lds((const __attribute__((address_space(1))) void*)g,
                                   (__attribute__((address_space(3))) void*)l, 16, 0, 0);
}

// K1: fused prep. blocks [0,8000): 4 vocab rows -> ebf + inv_norm.
//     blocks [8000,10048): ONE preds row -> o_rows, u_bf, cos_tgt (light regs).
__global__ __launch_bounds__(256) void prep_all(
    const float* __restrict__ preds, const float* __restrict__ emb,
    const int* __restrict__ target,
    float* __restrict__ o_rows, short* __restrict__ u_bf,
    float* __restrict__ cos_tgt, short* __restrict__ ebf,
    float* __restrict__ inv_norm) {
  int tid = threadIdx.x;
  int wave = tid >> 6, lane = tid & 63;
  if (blockIdx.x < VOC_BLOCKS) {
    int v = blockIdx.x * 4 + wave;
    const float* e = emb + (size_t)v * Dd;
    float4 x0 = *(const float4*)(e + lane * 8);
    float4 x1 = *(const float4*)(e + lane * 8 + 4);
    float ss = x0.x * x0.x + x0.y * x0.y + x0.z * x0.z + x0.w * x0.w +
               x1.x * x1.x + x1.y * x1.y + x1.z * x1.z + x1.w * x1.w;
    ss = waveReduceSum(ss);
    float inv = 1.0f / fmaxf(sqrtf(ss), 1e-12f);
    bf16x8 o;
    o[0] = (short)f2bf(x0.x * inv); o[1] = (short)f2bf(x0.y * inv);
    o[2] = (short)f2bf(x0.z * inv); o[3] = (short)f2bf(x0.w * inv);
    o[4] = (short)f2bf(x1.x * inv); o[5] = (short)f2bf(x1.y * inv);
    o[6] = (short)f2bf(x1.z * inv); o[7] = (short)f2bf(x1.w * inv);
    *(bf16x8*)(ebf + (size_t)v * Dd + lane * 8) = o;
    if (lane == 0) inv_norm[v] = inv;
  } else {
    int row = blockIdx.x - VOC_BLOCKS;
    int b = row >> 9, s = row & (Ss - 1);
    const float* p = preds + (size_t)b * Dd * Ss + s;
    float x0 = p[(size_t)tid * Ss];
    float x1 = p[(size_t)(tid + 256) * Ss];
    __shared__ float red[12];
    float ss = waveReduceSum(x0 * x0 + x1 * x1);
    if (lane == 0) red[wave] = ss;
    __syncthreads();
    float inv = 1.0f / fmaxf(sqrtf(red[0] + red[1] + red[2] + red[3]), 1e-12f);
    float o0 = x0 * inv, o1 = x1 * inv;
    o_rows[(size_t)row * Dd + tid] = o0;
    o_rows[(size_t)row * Dd + tid + 256] = o1;
    int t = target[row];
    const float* et = emb + (size_t)t * Dd;
    float e0 = et[tid], e1 = et[tid + 256];
    u_bf[(size_t)row * Dd + tid] = (short)f2bf(o0 - e0);
    u_bf[(size_t)row * Dd + tid + 256] = (short)f2bf(o1 - e1);
    float ss2 = waveReduceSum(e0 * e0 + e1 * e1);
    float dt = waveReduceSum(o0 * e0 + o1 * e1);
    if (lane == 0) { red[4 + wave] = ss2; red[8 + wave] = dt; }
    __syncthreads();
    if (tid == 0) {
      float n2 = red[4] + red[5] + red[6] + red[7];
      float dd = red[8] + red[9] + red[10] + red[11];
      cos_tgt[row] = dd * (1.0f / fmaxf(sqrtf(n2), 1e-12f));
    }
  }
}

// K2: 128x128-tile bf16 MFMA GEMM (B^T), BK=64, XOR bank swizzle, XCD strips,
// + argmax epilogue. Two fragment-load halves share ONE register set. (R9)
__global__ __launch_bounds__(256, 4) void gemm_argmax(
    const short* __restrict__ u_bf, const short* __restrict__ ebf,
    unsigned long long* __restrict__ part) {
  __shared__ short sA[128 * 64];  // 16 KB
  __shared__ short sB[128 * 64];  // 16 KB
  int bid = blockIdx.x;
  int g = (bid & 7) * 500 + (bid >> 3);
  int tm = g & 15, tn = g >> 4;
  int tid = threadIdx.x;
  int w = tid >> 6, lane = tid & 63;
  int wm = w >> 1, wn = w & 1;

  // staging: glds dest = wave-base + lane*16 -> row = lane>>3, chunk = lane&7.
  // lane sources GLOBAL chunk (lane&7)^((lane>>3)&7): physical chunk (lane&7)
  // of row r holds logical chunk (lane&7)^(r&7).
  int srow = w * 8 + (lane >> 3);
  int schunk = (lane & 7) ^ ((lane >> 3) & 7);
  const short* gA = u_bf + (size_t)(tm * 128 + srow) * Dd + schunk * 8;
  const short* gB = ebf + (size_t)(tn * 128 + srow) * Dd + schunk * 8;

  // fragment read: row fr, k-quad q = lane>>4; logical chunk kc*4+q ->
  // physical (kc*4+q)^(fr&7).
  int fr = lane & 15;
  int q = lane >> 4;
  int ck0 = ((q) ^ (fr & 7)) * 8;
  int ck1 = ((4 + q) ^ (fr & 7)) * 8;

  f32x4 acc[4][4];
  f32x4 z = {0.f, 0.f, 0.f, 0.f};
#pragma unroll
  for (int mi = 0; mi < 4; ++mi)
#pragma unroll
    for (int ni = 0; ni < 4; ++ni) acc[mi][ni] = z;

  for (int kk = 0; kk < Dd / 64; ++kk) {
    __syncthreads();  // previous compute done before overwrite
    {
      const short* ga = gA + kk * 64;
      const short* gb = gB + kk * 64;
#pragma unroll
      for (int i = 0; i < 4; ++i) {
        async_ld16(ga + (size_t)(i * 32) * Dd, &sA[(w * 8 + i * 32) * 64]);
        async_ld16(gb + (size_t)(i * 32) * Dd, &sB[(w * 8 + i * 32) * 64]);
      }
    }
    __syncthreads();  // staging visible (vmcnt drained by barrier)
    bf16x8 af[4], bg[4];
    // half 0 (kc=0)
#pragma unroll
    for (int mi = 0; mi < 4; ++mi)
      af[mi] = *(const bf16x8*)(sA + (wm * 64 + mi * 16 + fr) * 64 + ck0);
#pragma unroll
    for (int ni = 0; ni < 4; ++ni)
      bg[ni] = *(const bf16x8*)(sB + (wn * 64 + ni * 16 + fr) * 64 + ck0);
#pragma unroll
    for (int mi = 0; mi < 4; ++mi)
#pragma unroll
      for (int ni = 0; ni < 4; ++ni)
        acc[mi][ni] = __builtin_amdgcn_mfma_f32_16x16x32_bf16(af[mi], bg[ni], acc[mi][ni], 0, 0, 0);
    // half 1 (kc=1) — reuse the same registers
#pragma unroll
    for (int mi = 0; mi < 4; ++mi)
      af[mi] = *(const bf16x8*)(sA + (wm * 64 + mi * 16 + fr) * 64 + ck1);
#pragma unroll
    for (int ni = 0; ni < 4; ++ni)
      bg[ni] = *(const bf16x8*)(sB + (wn * 64 + ni * 16 + fr) * 64 + ck1);
#pragma unroll
    for (int mi = 0; mi < 4; ++mi)
#pragma unroll
      for (int ni = 0; ni < 4; ++ni)
        acc[mi][ni] = __builtin_amdgcn_mfma_f32_16x16x32_bf16(af[mi], bg[ni], acc[mi][ni], 0, 0, 0);
  }

  // ---- argmax epilogue ----
  // C layout: col = lane&15, row = (lane>>4)*4 + reg
  float bs[4][4];
  int bc[4][4];
  int col0 = tn * 128 + wn * 64 + (lane & 15);
#pragma unroll
  for (int mi = 0; mi < 4; ++mi) {
#pragma unroll
    for (int j = 0; j < 4; ++j) { bs[mi][j] = acc[mi][0][j]; bc[mi][j] = col0; }
#pragma unroll
    for (int ni = 1; ni < 4; ++ni) {
      int c = col0 + ni * 16;
#pragma unroll
      for (int j = 0; j < 4; ++j) {
        float v = acc[mi][ni][j];
        if (v > bs[mi][j]) { bs[mi][j] = v; bc[mi][j] = c; }  // strict >: earliest col kept
      }
    }
  }
  // butterfly across the 16 cols (masks 1,2,4,8 stay within the 16-lane group)
#pragma unroll
  for (int m = 1; m < 16; m <<= 1) {
#pragma unroll
    for (int mi = 0; mi < 4; ++mi)
#pragma unroll
      for (int j = 0; j < 4; ++j) {
        float os = __shfl_xor(bs[mi][j], m, 64);
        int oc = __shfl_xor(bc[mi][j], m, 64);
        if (os > bs[mi][j] || (os == bs[mi][j] && oc < bc[mi][j])) {
          bs[mi][j] = os;
          bc[mi][j] = oc;
        }
      }
  }
  // merge the two col-half waves (wn=0/1) via LDS, one packed write per row
  __syncthreads();  // done reading sA/sB; reuse as merge scratch
  float* sEs = (float*)sA;          // [2][128]
  int* sEc = (int*)sA + 256;        // [2][128]
  if ((lane & 15) == 0) {
    int qq = lane >> 4;
#pragma unroll
    for (int mi = 0; mi < 4; ++mi)
#pragma unroll
      for (int j = 0; j < 4; ++j) {
        int rloc = wm * 64 + mi * 16 + qq * 4 + j;
        sEs[wn * 128 + rloc] = bs[mi][j];
        sEc[wn * 128 + rloc] = bc[mi][j];
      }
  }
  __syncthreads();
  if (tid < 128) {
    float s0 = sEs[tid], s1 = sEs[128 + tid];
    int c0 = sEc[tid], c1 = sEc[128 + tid];
    if (s1 > s0 || (s1 == s0 && c1 < c0)) { s0 = s1; c0 = c1; }
    part[(size_t)tn * ROWS + tm * 128 + tid] = packSC(s0, c0);
  }
}

// D: per row — u64-max merge 250 partials, recompute cos at jmax in fp32, hinge.
__global__ __launch_bounds__(256) void row_final(
    const float* __restrict__ o_rows, const float* __restrict__ emb,
    const float* __restrict__ inv_norm, const float* __restrict__ cos_tgt,
    const int* __restrict__ target, const int* __restrict__ pad_id,
    const unsigned long long* __restrict__ part, float* __restrict__ diffs) {
  int wave = threadIdx.x >> 6, lane = threadIdx.x & 63;
  int row = blockIdx.x * 4 + wave;
  unsigned long long best = 0ull;  // any real packed value exceeds 0
  for (int t = lane; t < NTILE_N; t += 64) {
    unsigned long long p = part[(size_t)t * ROWS + row];
    if (p > best) best = p;
  }
#pragma unroll
  for (int m = 1; m < 64; m <<= 1) {
    unsigned long long o = __shfl_xor(best, m, 64);
    if (o > best) best = o;
  }
  int bi = (int)(~(unsigned)(best & 0xFFFFFFFFull));
  const float* o = o_rows + (size_t)row * Dd;
  const float* e = emb + (size_t)bi * Dd;
  float d = 0.f;
#pragma unroll
  for (int i = 0; i < Dd / 64; ++i) d += o[lane + 64 * i] * e[lane + 64 * i];
  d = waveReduceSum(d);
  if (lane == 0) {
    float cmax = d * inv_norm[bi];
    int t = target[row];
    float df = fmaxf(0.5f + cmax - cos_tgt[row], 0.0f);
    diffs[row] = (t != pad_id[0]) ? df : 0.0f;
  }
}

// F: masked mean.
__global__ __launch_bounds__(256) void reduce_final(
    const float* __restrict__ diffs, const int* __restrict__ target,
    const int* __restrict__ pad_id, float* __restrict__ out) {
  int tid = threadIdx.x;
  int pid = pad_id[0];
  float s = 0.f, c = 0.f;
  for (int i = tid; i < ROWS; i += 256) {
    s += diffs[i];
    c += (target[i] != pid) ? 1.0f : 0.0f;
  }
  s = waveReduceSum(s);
  c = waveReduceSum(c);
  __shared__ float rs[4], rc[4];
  int wave = tid >> 6, lane = tid & 63;
  if (lane == 0) { rs[wave] = s; rc[wave] = c; }
  __syncthreads();
  if (tid == 0) out[0] = (rs[0] + rs[1] + rs[2] + rs[3]) / (rc[0] + rc[1] + rc[2] + rc[3]);
}

extern "C" void kernel_launch(void* const* d_in, const int* in_sizes, int n_in,
                              void* d_out, int out_size, void* d_ws, size_t ws_size,
                              hipStream_t stream) {
  const float* preds = (const float*)d_in[0];
  const float* emb = (const float*)d_in[1];
  const int* target = (const int*)d_in[2];
  const int* pad_id = (const int*)d_in[3];
  char* ws = (char*)d_ws;
  // ws layout (bytes), total ~43.3 MB
  float* o_rows = (float*)ws;                               // 2048*512*4 = 4,194,304
  short* u_bf = (short*)(ws + 4194304);                     // 2048*512*2 = 2,097,152
  short* ebf = (short*)(ws + 6291456);                      // 32000*512*2 = 32,768,000
  float* inv_norm = (float*)(ws + 39059456);                // 32000*4 = 128,000
  float* cos_tgt = (float*)(ws + 39187456);                 // 2048*4
  unsigned long long* part = (unsigned long long*)(ws + 39195648);  // 250*2048*8 = 4,096,000
  float* diffs = (float*)(ws + 43291648);                   // 2048*4

  prep_all<<<VOC_BLOCKS + ROWS, 256, 0, stream>>>(preds, emb, target, o_rows, u_bf,
                                                  cos_tgt, ebf, inv_norm);
  gemm_argmax<<<NTILE_M * NTILE_N, 256, 0, stream>>>(u_bf, ebf, part);
  row_final<<<ROWS / 4, 256, 0, stream>>>(o_rows, emb, inv_norm, cos_tgt, target,
                                          pad_id, part, diffs);
  reduce_final<<<1, 256, 0, stream>>>(diffs, target, pad_id, (float*)d_out);
}